// Round 6
// baseline (802.695 us; speedup 1.0000x reference)
//
#include <hip/hip_runtime.h>

// Fused SDPA, MI355X gfx950. G=32, H=8, L=512, D=64.
// q:(G,H,L,D) f32, k:(G,H,D,L) f32, v:(G,H,L,D) f32, mask:(8,L,L) int
// (nonzero = masked), out:(G,H,L,D) f32.
//
// Round 6: double-buffered pipeline with SHORT prefetch live ranges.
// R3-R5 all spilled (~200MB scratch) because prefetch arrays spanned a full
// tile of compute on top of o(32)+qf(16)+sc(16)+addr(~14). Now each prefetch
// is issued one compute-phase before its pack+write:
//   [K16 issue] GEMM1mt0 [K pack/write, V0 issue] exp+GEMM2mt0
//   GEMM1mt1 [V0 pack/write, V1 issue] exp+GEMM2mt1 [V1 pack/write] barrier
// Peak live ~100 VGPR < 128 cap (256 thr x 4 blocks/CU). One barrier/iter.

typedef __attribute__((ext_vector_type(8)))  short bf16x8;
typedef __attribute__((ext_vector_type(16))) float f32x16;

union Frag4 { uint4 x; unsigned u[4]; bf16x8 v; };

__device__ __forceinline__ unsigned pk_bf16(float a, float b){
    unsigned ua = __builtin_bit_cast(unsigned, a) + 0x8000u;
    unsigned ub = __builtin_bit_cast(unsigned, b) + 0x8000u;
    return __builtin_amdgcn_perm(ub, ua, 0x07060302u);
}

__device__ __forceinline__ float fast_exp2(float x){
#if __has_builtin(__builtin_amdgcn_exp2f)
    return __builtin_amdgcn_exp2f(x);
#else
    return exp2f(x);
#endif
}

#define SCL 0.1803368801111204f   // 0.125 * log2(e): GEMM1 output is exp2-ready

// ---- prepass: mask (8,512,512) int -> bitmask (8,512,8) uint64 ----
__global__ __launch_bounds__(256)
void mask_prepass(const int* __restrict__ mg, unsigned long long* __restrict__ bm)
{
    const int gid  = blockIdx.x*256 + threadIdx.x;
    const int wid  = gid >> 6;          // (b*512+row)*8 + chunk
    const int lane = gid & 63;
    const int chunk = wid & 7;
    const int rowb  = wid >> 3;
    const int x = mg[(size_t)rowb*512 + chunk*64 + lane];
    unsigned long long m = __ballot(x != 0);
    if (lane == 0) bm[wid] = m;
}

template<bool USE_BM>
__global__ __launch_bounds__(256, 4)
void attn_fused(const float* __restrict__ qg, const float* __restrict__ kg,
                const float* __restrict__ vg, const int* __restrict__ mg,
                const unsigned long long* __restrict__ bmg,
                float* __restrict__ og)
{
    __shared__ uint4 sKt4[2][64*8];   // Kt[m][d-octet g^(m&7)]  2 x 8 KiB
    __shared__ uint4 sVt4[2][64*8];   // Vt[d][m-octet g^(d&7)]  2 x 8 KiB

    const int t    = threadIdx.x;
    const int lane = t & 63;
    const int wv   = t >> 6;
    const int col  = lane & 31;
    const int h    = lane >> 5;

    const int bi   = blockIdx.x;
    const int s    = bi >> 3;
    const int head = (bi & 7)*32 + (s >> 2);   // XCD-affine: bi&7 == XCD id
    const int qt   = s & 3;
    const int b    = bi & 7;

    const int qrl = qt*128 + wv*32 + col;      // this lane's q-row in [0,512)

    // staging pointers (pointer-bumped per chunk)
    const float* kp0 = kg + (size_t)head*32768 + (size_t)(wv*8)*512 + lane;
    const float* kp1 = kp0 + (size_t)8*4*512;
    const float* vp0 = vg + (size_t)head*32768 + (size_t)(wv*8)*64 + lane;
    const float* vp1 = vp0 + (size_t)8*4*64;
    const unsigned long long* bmrow = bmg + ((size_t)(b*512) + qrl)*8;
    const int* mrow = mg + (size_t)b*262144 + (size_t)qrl*512;

    // constant LDS write slots for this thread's two octet-groups
    const int wi0 = lane*8 + ((wv  ) ^ (lane&7));
    const int wi1 = lane*8 + ((wv+4) ^ (lane&7));

    // ---- persistent Q B-fragments, pre-scaled by 0.125*log2e ----
    Frag4 qf[4];
    {
        const float* qr = qg + (size_t)head*32768 + (size_t)qrl*64 + h*8;
        #pragma unroll
        for (int kt=0; kt<4; ++kt){
            float4 x0 = *(const float4*)(qr + kt*16);
            float4 x1 = *(const float4*)(qr + kt*16 + 4);
            qf[kt].u[0] = pk_bf16(x0.x*SCL, x0.y*SCL);
            qf[kt].u[1] = pk_bf16(x0.z*SCL, x0.w*SCL);
            qf[kt].u[2] = pk_bf16(x1.x*SCL, x1.y*SCL);
            qf[kt].u[3] = pk_bf16(x1.z*SCL, x1.w*SCL);
        }
    }

    f32x16 o0, o1;
    #pragma unroll
    for (int i=0;i<16;++i){ o0[i]=0.f; o1[i]=0.f; }
    float lsum = 0.f;

    // ---- prologue: stage chunk 0 into buffer 0 ----
    {
        float a[8], c[8];
        #pragma unroll
        for (int dd=0; dd<8; ++dd){ a[dd]=kp0[(size_t)dd*512]; c[dd]=kp1[(size_t)dd*512]; }
        Frag4 w0, w1;
        #pragma unroll
        for (int j=0; j<4; ++j){ w0.u[j]=pk_bf16(a[2*j],a[2*j+1]); w1.u[j]=pk_bf16(c[2*j],c[2*j+1]); }
        sKt4[0][wi0] = w0.x;  sKt4[0][wi1] = w1.x;
        #pragma unroll
        for (int mm=0; mm<8; ++mm){ a[mm]=vp0[(size_t)mm*64]; c[mm]=vp1[(size_t)mm*64]; }
        #pragma unroll
        for (int j=0; j<4; ++j){ w0.u[j]=pk_bf16(a[2*j],a[2*j+1]); w1.u[j]=pk_bf16(c[2*j],c[2*j+1]); }
        sVt4[0][wi0] = w0.x;  sVt4[0][wi1] = w1.x;
    }
    unsigned long long bmCur = USE_BM ? bmrow[0] : 0ull;
    kp0 += 64; kp1 += 64; vp0 += 4096; vp1 += 4096;
    __syncthreads();

    #pragma unroll 1
    for (int kb=0; kb<8; ++kb){
        const uint4* rK = sKt4[kb & 1];
        const uint4* rV = sVt4[kb & 1];
        uint4*       wK = sKt4[(kb & 1) ^ 1];
        uint4*       wV = sVt4[(kb & 1) ^ 1];
        const bool  pre = (kb < 7);

        // -- A: issue next-K loads (16 f32) + next bitmask
        float nk0[8], nk1[8];
        unsigned long long bmNext = 0ull;
        if (pre){
            #pragma unroll
            for (int dd=0; dd<8; ++dd){ nk0[dd]=kp0[(size_t)dd*512]; nk1[dd]=kp1[(size_t)dd*512]; }
            if (USE_BM) bmNext = bmrow[kb+1];
        }

        // -- B: GEMM1 mt=0 (covers K load latency)
        f32x16 sc;
        #pragma unroll
        for (int i=0;i<16;++i) sc[i]=0.f;
        #pragma unroll
        for (int kt=0; kt<4; ++kt){
            Frag4 a; a.x = rK[col*8 + ((kt*2+h) ^ (col&7))];
            sc = __builtin_amdgcn_mfma_f32_32x32x16_bf16(a.v, qf[kt].v, sc, 0, 0, 0);
        }

        // -- C: pack+write K, issue V half-0 loads (8 f32)
        float nv0[8];
        if (pre){
            Frag4 w0, w1;
            #pragma unroll
            for (int j=0; j<4; ++j){ w0.u[j]=pk_bf16(nk0[2*j],nk0[2*j+1]); w1.u[j]=pk_bf16(nk1[2*j],nk1[2*j+1]); }
            wK[wi0] = w0.x;  wK[wi1] = w1.x;
            #pragma unroll
            for (int mm=0; mm<8; ++mm) nv0[mm] = vp0[(size_t)mm*64];
        }

        // -- D: exp + pack + GEMM2 for mt=0 (covers V0 latency)
        {
            const unsigned wbits = USE_BM ? (unsigned)bmCur : 0u;
            unsigned pp[8];
            #pragma unroll
            for (int rg=0; rg<4; ++rg){
                float e0,e1,e2,e3;
                if (USE_BM){
                    const unsigned b4 = wbits >> (8*rg + 4*h);
                    e0 = (b4 & 1u) ? 0.f : fast_exp2(sc[4*rg+0]);
                    e1 = (b4 & 2u) ? 0.f : fast_exp2(sc[4*rg+1]);
                    e2 = (b4 & 4u) ? 0.f : fast_exp2(sc[4*rg+2]);
                    e3 = (b4 & 8u) ? 0.f : fast_exp2(sc[4*rg+3]);
                } else {
                    int4 mm = *(const int4*)(mrow + rg*8 + h*4);
                    e0 = mm.x ? 0.f : fast_exp2(sc[4*rg+0]);
                    e1 = mm.y ? 0.f : fast_exp2(sc[4*rg+1]);
                    e2 = mm.z ? 0.f : fast_exp2(sc[4*rg+2]);
                    e3 = mm.w ? 0.f : fast_exp2(sc[4*rg+3]);
                }
                lsum += (e0+e1)+(e2+e3);
                pp[2*rg+0] = pk_bf16(e0,e1);
                pp[2*rg+1] = pk_bf16(e2,e3);
            }
            #pragma unroll
            for (int c=0; c<2; ++c){
                unsigned keep0 = h ? pp[4*c+2] : pp[4*c+0];
                unsigned keep1 = h ? pp[4*c+3] : pp[4*c+1];
                unsigned give0 = h ? pp[4*c+0] : pp[4*c+2];
                unsigned give1 = h ? pp[4*c+1] : pp[4*c+3];
                unsigned got0 = (unsigned)__shfl_xor((int)give0, 32, 64);
                unsigned got1 = (unsigned)__shfl_xor((int)give1, 32, 64);
                Frag4 pa;
                pa.u[0] = h ? got0  : keep0;
                pa.u[1] = h ? got1  : keep1;
                pa.u[2] = h ? keep0 : got0;
                pa.u[3] = h ? keep1 : got1;
                const int gm = c*2 + h;
                Frag4 b0; b0.x = rV[col*8      + (gm ^ (col&7))];
                o0 = __builtin_amdgcn_mfma_f32_32x32x16_bf16(pa.v, b0.v, o0, 0, 0, 0);
                Frag4 b1; b1.x = rV[(32+col)*8 + (gm ^ ((32+col)&7))];
                o1 = __builtin_amdgcn_mfma_f32_32x32x16_bf16(pa.v, b1.v, o1, 0, 0, 0);
            }
        }

        // -- E: GEMM1 mt=1
        #pragma unroll
        for (int i=0;i<16;++i) sc[i]=0.f;
        #pragma unroll
        for (int kt=0; kt<4; ++kt){
            const int r = 32 + col;
            Frag4 a; a.x = rK[r*8 + ((kt*2+h) ^ (r&7))];
            sc = __builtin_amdgcn_mfma_f32_32x32x16_bf16(a.v, qf[kt].v, sc, 0, 0, 0);
        }

        // -- F: pack+write V0, issue V half-1 loads (8 f32)
        float nv1[8];
        if (pre){
            Frag4 w0;
            #pragma unroll
            for (int j=0; j<4; ++j) w0.u[j]=pk_bf16(nv0[2*j],nv0[2*j+1]);
            wV[wi0] = w0.x;
            #pragma unroll
            for (int mm=0; mm<8; ++mm) nv1[mm] = vp1[(size_t)mm*64];
        }

        // -- G: exp + pack + GEMM2 for mt=1 (covers V1 latency)
        {
            const unsigned wbits = USE_BM ? (unsigned)(bmCur >> 32) : 0u;
            unsigned pp[8];
            #pragma unroll
            for (int rg=0; rg<4; ++rg){
                float e0,e1,e2,e3;
                if (USE_BM){
                    const unsigned b4 = wbits >> (8*rg + 4*h);
                    e0 = (b4 & 1u) ? 0.f : fast_exp2(sc[4*rg+0]);
                    e1 = (b4 & 2u) ? 0.f : fast_exp2(sc[4*rg+1]);
                    e2 = (b4 & 4u) ? 0.f : fast_exp2(sc[4*rg+2]);
                    e3 = (b4 & 8u) ? 0.f : fast_exp2(sc[4*rg+3]);
                } else {
                    int4 mm = *(const int4*)(mrow + 32 + rg*8 + h*4);
                    e0 = mm.x ? 0.f : fast_exp2(sc[4*rg+0]);
                    e1 = mm.y ? 0.f : fast_exp2(sc[4*rg+1]);
                    e2 = mm.z ? 0.f : fast_exp2(sc[4*rg+2]);
                    e3 = mm.w ? 0.f : fast_exp2(sc[4*rg+3]);
                }
                lsum += (e0+e1)+(e2+e3);
                pp[2*rg+0] = pk_bf16(e0,e1);
                pp[2*rg+1] = pk_bf16(e2,e3);
            }
            #pragma unroll
            for (int c=0; c<2; ++c){
                unsigned keep0 = h ? pp[4*c+2] : pp[4*c+0];
                unsigned keep1 = h ? pp[4*c+3] : pp[4*c+1];
                unsigned give0 = h ? pp[4*c+0] : pp[4*c+2];
                unsigned give1 = h ? pp[4*c+1] : pp[4*c+3];
                unsigned got0 = (unsigned)__shfl_xor((int)give0, 32, 64);
                unsigned got1 = (unsigned)__shfl_xor((int)give1, 32, 64);
                Frag4 pa;
                pa.u[0] = h ? got0  : keep0;
                pa.u[1] = h ? got1  : keep1;
                pa.u[2] = h ? keep0 : got0;
                pa.u[3] = h ? keep1 : got1;
                const int gm = 4 + c*2 + h;
                Frag4 b0; b0.x = rV[col*8      + (gm ^ (col&7))];
                o0 = __builtin_amdgcn_mfma_f32_32x32x16_bf16(pa.v, b0.v, o0, 0, 0, 0);
                Frag4 b1; b1.x = rV[(32+col)*8 + (gm ^ ((32+col)&7))];
                o1 = __builtin_amdgcn_mfma_f32_32x32x16_bf16(pa.v, b1.v, o1, 0, 0, 0);
            }
        }

        // -- H: pack+write V1, one barrier, advance
        if (pre){
            Frag4 w1;
            #pragma unroll
            for (int j=0; j<4; ++j) w1.u[j]=pk_bf16(nv1[2*j],nv1[2*j+1]);
            wV[wi1] = w1.x;
            __syncthreads();
        }
        bmCur = bmNext;
        kp0 += 64; kp1 += 64; vp0 += 4096; vp1 += 4096;
        if (!USE_BM) mrow += 64;
    }

    // ---- normalize + direct coalesced stores ----
    lsum += __shfl_xor(lsum, 32, 64);
    const float inv = 1.0f / lsum;
    float* ob = og + (size_t)head*32768 + (size_t)(qt*128 + wv*32)*64;
    #pragma unroll
    for (int r=0; r<16; ++r){
        const int qq = (r&3) + 8*(r>>2) + 4*h;
        const float iv = __shfl(inv, qq, 64);
        ob[(size_t)qq*64 + col]      = o0[r]*iv;
        ob[(size_t)qq*64 + 32 + col] = o1[r]*iv;
    }
}

extern "C" void kernel_launch(void* const* d_in, const int* in_sizes, int n_in,
                              void* d_out, int out_size, void* d_ws, size_t ws_size,
                              hipStream_t stream) {
    (void)in_sizes; (void)n_in; (void)out_size;
    const float* q = (const float*)d_in[0];
    const float* k = (const float*)d_in[1];
    const float* v = (const float*)d_in[2];
    const int*   m = (const int*)d_in[3];
    const size_t bm_bytes = (size_t)8*512*8*sizeof(unsigned long long); // 256 KB
    if (ws_size >= bm_bytes){
        unsigned long long* bm = (unsigned long long*)d_ws;
        mask_prepass<<<dim3(8192), dim3(256), 0, stream>>>(m, bm);
        attn_fused<true><<<dim3(1024), dim3(256), 0, stream>>>(q, k, v, m, bm, (float*)d_out);
    } else {
        attn_fused<false><<<dim3(1024), dim3(256), 0, stream>>>(q, k, v, m, nullptr, (float*)d_out);
    }
}